// Round 14
// baseline (2184.334 us; speedup 1.0000x reference)
//
#include <hip/hip_runtime.h>
#include <hip/hip_bf16.h>
#include <cstddef>

#define B 256
#define S 128
#define H 512
#define G 2048

typedef __attribute__((ext_vector_type(8))) short short8;
typedef __attribute__((ext_vector_type(4))) float f32x4;

__device__ __forceinline__ float sigmoidf_(float x){ return 1.f/(1.f+expf(-x)); }
__device__ __forceinline__ float bf2f_(unsigned short u){ return __uint_as_float(((unsigned)u) << 16); }

// ---------------- init: zero c, h16A, h16B, flags; y = future_init_outcome ----------------
__global__ void init_kernel(float* __restrict__ c, unsigned* __restrict__ h16A_u,
                            unsigned* __restrict__ h16B_u, int* __restrict__ flg,
                            float* __restrict__ y, const float* __restrict__ fio){
  int i = blockIdx.x*blockDim.x + threadIdx.x;
  if (i < B*H) c[i] = 0.f;
  if (i < B*H/2){ h16A_u[i] = 0u; h16B_u[i] = 0u; }
  if (i < 512) flg[i] = 0;
  if (i < B) y[i] = fio[i];
}

// ------- e_x v4 (r13 verbatim) -------
__global__ __launch_bounds__(128) void embed_x4(const float* __restrict__ tx,
    const float* __restrict__ W, const float* __restrict__ bvec,
    __hip_bfloat16* __restrict__ ex16){
  __shared__ float xs[16][64];
  const int tid = threadIdx.x;
  float w[64];
  #pragma unroll
  for (int k = 0; k < 64; ++k) w[k] = W[k*128 + tid];
  const float bj = bvec[tid];
  const int r0 = blockIdx.x * 16;
  {
    const float4* src = (const float4*)&tx[(size_t)r0*64];
    float4* dst = (float4*)&xs[0][0];
    dst[tid] = src[tid];
    dst[tid + 128] = src[tid + 128];
  }
  __syncthreads();
  #pragma unroll
  for (int r = 0; r < 16; ++r){
    const float4* xr = (const float4*)&xs[r][0];
    float a0 = 0.f, a1 = 0.f, a2 = 0.f, a3 = 0.f;
    #pragma unroll
    for (int q = 0; q < 16; ++q){
      float4 xv = xr[q];
      a0 += xv.x*w[q*4+0];
      a1 += xv.y*w[q*4+1];
      a2 += xv.z*w[q*4+2];
      a3 += xv.w*w[q*4+3];
    }
    float a = bj + (a0 + a1) + (a2 + a3);
    ex16[(size_t)(r0 + r)*128 + tid] = __float2bfloat16(fmaxf(a, 0.f));
  }
}

// ---------------- e_d (r13 verbatim) ----------------
__global__ __launch_bounds__(128) void embed_d_kernel(const float* __restrict__ sx,
    const float* __restrict__ W, const float* __restrict__ bvec, float* __restrict__ ed){
  __shared__ float xs[32];
  int b = blockIdx.x, j = threadIdx.x;
  if (j < 32) xs[j] = sx[(size_t)b*32 + j];
  __syncthreads();
  float a = bvec[j];
  #pragma unroll 8
  for (int k = 0; k < 32; ++k) a += xs[k]*W[k*128 + j];
  ed[(size_t)b*128 + j] = fmaxf(a, 0.f);
}

// ---- gd2 (r13 verbatim) ----
__global__ __launch_bounds__(256) void gd2_kernel(const float* __restrict__ ed,
    const float* __restrict__ We, const float* __restrict__ be,
    const float* __restrict__ Wd, const float* __restrict__ bd,
    float* __restrict__ gde, float* __restrict__ gdd){
  __shared__ float eds[128];
  int b = blockIdx.x, tid = threadIdx.x;
  if (tid < 128) eds[tid] = ed[(size_t)b*128 + tid];
  __syncthreads();
  int n = blockIdx.y*256 + tid;
  float ae = be[n], ad = bd[n];
  #pragma unroll 4
  for (int k = 0; k < 128; ++k){
    float e = eds[k];
    ae += e*We[(size_t)(128 + k)*G + n];
    ad += e*Wd[(size_t)k*G + n];
  }
  gde[(size_t)b*G + n] = ae;
  gdd[(size_t)b*G + n] = ad;
}

// ---- weight transpose (r13 verbatim) ----
__global__ __launch_bounds__(256) void wtrans_kernel(
    const float* __restrict__ A, int rowsA, const float* __restrict__ Bm,
    __hip_bfloat16* __restrict__ dst, int Ktot)
{
  __shared__ float tile[64][65];
  const int k0 = blockIdx.x*64, n0 = blockIdx.y*64;
  const int tid = threadIdx.x;
  const int tn = tid & 63, tq = tid >> 6;
  #pragma unroll
  for (int i = 0; i < 16; ++i){
    int k = k0 + tq*16 + i;
    float v = (k < rowsA) ? A[(size_t)k*G + n0 + tn] : Bm[(size_t)(k-rowsA)*G + n0 + tn];
    tile[k - k0][tn] = v;
  }
  __syncthreads();
  #pragma unroll
  for (int i = 0; i < 16; ++i){
    int n = n0 + tq*16 + i;
    dst[(size_t)n*Ktot + k0 + tn] = __float2bfloat16(tile[tn][tq*16 + i]);
  }
}

// ======== persistent encoder v2: flag-synced, no fences, L2 stays hot ========
// 256 blocks (cooperative, 1/CU) x 512 thr. v7 tile: 64b x 32 gate-cols, K-split 2.
// h exchanged via AGENT-scope atomics (coherence point); flags per (t, bgrp).
__global__ __launch_bounds__(512) void enc_persist2(
    const __hip_bfloat16* __restrict__ ex16,   // [B][S][128]
    const __hip_bfloat16* __restrict__ W16,    // [2048][640] n-major
    const float* __restrict__ gd,              // [B][2048]
    const float* __restrict__ Wr256,           // fp32 row Wih[256][*]
    const float* __restrict__ hist,            // [B][S]
    float* __restrict__ cb,                    // final c out
    __hip_bfloat16* hA, __hip_bfloat16* hB,    // ping-pong via coherence point
    __hip_bfloat16* __restrict__ eo16,
    int* __restrict__ flg)                     // [S][4]
{
  __shared__ unsigned short hl[64*520];        // h slab, stride 520 (16B-aligned, 2-way banks)
  __shared__ float gsc[2][4][8][66];
  unsigned* hlu = (unsigned*)hl;               // 260 dwords/row

  const int tid = threadIdx.x;
  const int id  = blockIdx.x;
  const int xcd = id & 7, sub = id >> 3;
  const int jgrp = xcd*8 + (sub & 7);
  const int bgrp = sub >> 3;                   // 0..3
  const int b0 = bgrp*64, j0 = jgrp*8;
  const int l  = tid & 63;
  const int wid = tid >> 6;
  const int kh = wid & 1, wm = (wid >> 1) & 1, wn = wid >> 2;
  const int lr = l & 15, lkp = (l >> 4)*8;

  // epilogue ownership: 1 h-elem per thread
  const int jj_e = tid & 7, bl_e = tid >> 3;
  const int b_e = b0 + bl_e, j_e = j0 + jj_e;
  float gdv[4], wrv[4];
  #pragma unroll
  for (int g = 0; g < 4; ++g){
    gdv[g] = gd[(size_t)b_e*G + g*512 + j_e];
    wrv[g] = Wr256[g*512 + j_e];
  }
  float creg = 0.f;

  // MFMA operand pointers (fixed parts)
  const int rowA0 = b0 + wm*32 + lr;
  const int rowA1 = rowA0 + 16;
  const int cc = wn*16 + lr;
  const int bn = (cc >> 3)*512 + j0 + (cc & 7);
  const __hip_bfloat16* wp = &W16[(size_t)bn*640 + lkp];
  const unsigned short* hl0 = &hl[(wm*32 + lr)*520 + lkp];
  const unsigned short* hl1 = &hl[(wm*32 + 16 + lr)*520 + lkp];

  __hip_bfloat16* hb[2] = {hA, hB};

  for (int t = 0; t < S; ++t){
    // ---- stage h(t-1) slab (rows b0..b0+63, all 512 cols) into LDS
    if (t == 0){
      for (int i = tid; i < 64*260; i += 512) hlu[i] = 0u;
    } else {
      if (tid == 0){
        while (__hip_atomic_load(&flg[(t-1)*4 + bgrp], __ATOMIC_RELAXED,
                                 __HIP_MEMORY_SCOPE_AGENT) < 64)
          __builtin_amdgcn_s_sleep(2);
      }
      __syncthreads();
      const unsigned* hprev = (const unsigned*)hb[(t & 1) ^ 1];
      #pragma unroll
      for (int i = 0; i < 32; ++i){
        const int idx = i*512 + tid;
        const int row = idx >> 8, dcol = idx & 255;
        hlu[row*260 + dcol] = __hip_atomic_load(&hprev[(size_t)(b0+row)*256 + dcol],
                                                __ATOMIC_RELAXED, __HIP_MEMORY_SCOPE_AGENT);
      }
    }
    __syncthreads();

    // ---- MFMA (v7 mapping; A-h from LDS, A-ex + B-W from global/L2-hot)
    const __hip_bfloat16* ep0 = &ex16[((size_t)rowA0*S + t)*128 + lkp];
    const __hip_bfloat16* ep1 = &ex16[((size_t)rowA1*S + t)*128 + lkp];
    f32x4 acc0 = {0.f,0.f,0.f,0.f}, acc1 = {0.f,0.f,0.f,0.f};
    if (kh == 0){
      #pragma unroll
      for (int ch = 0; ch < 4; ++ch){
        short8 a0 = *(const short8*)&ep0[ch*32];
        short8 a1 = *(const short8*)&ep1[ch*32];
        short8 bv = *(const short8*)&wp[ch*32];
        acc0 = __builtin_amdgcn_mfma_f32_16x16x32_bf16(a0, bv, acc0, 0,0,0);
        acc1 = __builtin_amdgcn_mfma_f32_16x16x32_bf16(a1, bv, acc1, 0,0,0);
      }
      #pragma unroll
      for (int ch = 0; ch < 6; ++ch){
        short8 a0 = *(const short8*)&hl0[ch*32];
        short8 a1 = *(const short8*)&hl1[ch*32];
        short8 bv = *(const short8*)&wp[128 + ch*32];
        acc0 = __builtin_amdgcn_mfma_f32_16x16x32_bf16(a0, bv, acc0, 0,0,0);
        acc1 = __builtin_amdgcn_mfma_f32_16x16x32_bf16(a1, bv, acc1, 0,0,0);
      }
    } else {
      #pragma unroll
      for (int ch = 0; ch < 10; ++ch){
        short8 a0 = *(const short8*)&hl0[(6+ch)*32];
        short8 a1 = *(const short8*)&hl1[(6+ch)*32];
        short8 bv = *(const short8*)&wp[320 + ch*32];
        acc0 = __builtin_amdgcn_mfma_f32_16x16x32_bf16(a0, bv, acc0, 0,0,0);
        acc1 = __builtin_amdgcn_mfma_f32_16x16x32_bf16(a1, bv, acc1, 0,0,0);
      }
    }

    // gate partials -> LDS (v7 mapping)
    {
      const int jj = l & 7;
      const int g  = wn*2 + ((l>>3)&1);
      #pragma unroll
      for (int r = 0; r < 4; ++r){
        gsc[kh][g][jj][wm*32 +      (l>>4)*4 + r] = acc0[r];
        gsc[kh][g][jj][wm*32 + 16 + (l>>4)*4 + r] = acc1[r];
      }
    }
    __syncthreads();

    // ---- epilogue (v7 math; c in register)
    {
      const float hv_e = hist[(size_t)b_e*S + t];
      float gi = gsc[0][0][jj_e][bl_e] + gsc[1][0][jj_e][bl_e] + gdv[0] + hv_e*wrv[0];
      float gf = gsc[0][1][jj_e][bl_e] + gsc[1][1][jj_e][bl_e] + gdv[1] + hv_e*wrv[1];
      float gg = gsc[0][2][jj_e][bl_e] + gsc[1][2][jj_e][bl_e] + gdv[2] + hv_e*wrv[2];
      float go = gsc[0][3][jj_e][bl_e] + gsc[1][3][jj_e][bl_e] + gdv[3] + hv_e*wrv[3];
      float cn = sigmoidf_(gf)*creg + sigmoidf_(gi)*tanhf(gg);
      float hn = sigmoidf_(go)*tanhf(cn);
      creg = cn;
      __hip_bfloat16 hbf = __float2bfloat16(hn);
      eo16[((size_t)b_e*S + t)*H + j_e] = hbf;
      // paired dword agent-store of (j_e even, j_e odd)
      unsigned hu = (unsigned)*(unsigned short*)&hbf;
      unsigned up = __shfl_down(hu, 1);
      if (!(tid & 1)){
        unsigned* dstp = (unsigned*)((unsigned short*)hb[t & 1] + (size_t)b_e*H + j_e);
        __hip_atomic_store(dstp, hu | (up << 16), __ATOMIC_RELAXED, __HIP_MEMORY_SCOPE_AGENT);
      }
    }
    asm volatile("s_waitcnt vmcnt(0)" ::: "memory");
    __syncthreads();                       // all threads' h stores retired
    if (tid == 0)
      __hip_atomic_fetch_add(&flg[t*4 + bgrp], 1, __ATOMIC_RELAXED, __HIP_MEMORY_SCOPE_AGENT);
  }

  cb[(size_t)b_e*H + j_e] = creg;
}

// ======== fallback per-step encoder (r13 enc_step7 verbatim) ========
__global__ __launch_bounds__(512) void enc_step7(
    const __hip_bfloat16* __restrict__ ex16, const __hip_bfloat16* __restrict__ hin,
    int hs, const __hip_bfloat16* __restrict__ W16, const float* __restrict__ gd,
    const float* __restrict__ Wr256, const float* __restrict__ hist,
    float* __restrict__ c, __hip_bfloat16* __restrict__ eo16, int t)
{
  __shared__ float gsc[2][4][8][66];
  const int tid = threadIdx.x;
  const int id  = blockIdx.x;
  const int xcd = id & 7, sub = id >> 3;
  const int jgrp = xcd*8 + (sub & 7);
  const int bgrp = sub >> 3;
  const int b0 = bgrp*64, j0 = jgrp*8;
  const int l  = tid & 63;
  const int wid = tid >> 6;
  const int kh = wid & 1, wm = (wid >> 1) & 1, wn = wid >> 2;
  const int lr = l & 15, lkp = (l >> 4)*8;

  const int jj_e = tid & 7, bl_e = tid >> 3;
  const int b_e = b0 + bl_e, j_e = j0 + jj_e;
  const float hv_e = hist[(size_t)b_e*S + t];
  const float c_e  = c[(size_t)b_e*H + j_e];
  float gdv[4], wrv[4];
  #pragma unroll
  for (int g = 0; g < 4; ++g){
    gdv[g] = gd[(size_t)b_e*G + g*512 + j_e];
    wrv[g] = Wr256[g*512 + j_e];
  }

  const int rowA0 = b0 + wm*32 + lr;
  const int rowA1 = rowA0 + 16;
  const int cc = wn*16 + lr;
  const int bn = (cc >> 3)*512 + j0 + (cc & 7);

  const __hip_bfloat16* ep0 = &ex16[((size_t)rowA0*S + t)*128 + lkp];
  const __hip_bfloat16* ep1 = &ex16[((size_t)rowA1*S + t)*128 + lkp];
  const __hip_bfloat16* hp0 = &hin[(size_t)rowA0*hs + lkp];
  const __hip_bfloat16* hp1 = &hin[(size_t)rowA1*hs + lkp];
  const __hip_bfloat16* wp  = &W16[(size_t)bn*640 + lkp];

  f32x4 acc0 = {0.f,0.f,0.f,0.f}, acc1 = {0.f,0.f,0.f,0.f};
  if (kh == 0){
    #pragma unroll
    for (int ch = 0; ch < 4; ++ch){
      short8 a0 = *(const short8*)&ep0[ch*32];
      short8 a1 = *(const short8*)&ep1[ch*32];
      short8 bv = *(const short8*)&wp[ch*32];
      acc0 = __builtin_amdgcn_mfma_f32_16x16x32_bf16(a0, bv, acc0, 0,0,0);
      acc1 = __builtin_amdgcn_mfma_f32_16x16x32_bf16(a1, bv, acc1, 0,0,0);
    }
    #pragma unroll
    for (int ch = 0; ch < 6; ++ch){
      short8 a0 = *(const short8*)&hp0[ch*32];
      short8 a1 = *(const short8*)&hp1[ch*32];
      short8 bv = *(const short8*)&wp[128 + ch*32];
      acc0 = __builtin_amdgcn_mfma_f32_16x16x32_bf16(a0, bv, acc0, 0,0,0);
      acc1 = __builtin_amdgcn_mfma_f32_16x16x32_bf16(a1, bv, acc1, 0,0,0);
    }
  } else {
    #pragma unroll
    for (int ch = 0; ch < 10; ++ch){
      short8 a0 = *(const short8*)&hp0[(6+ch)*32];
      short8 a1 = *(const short8*)&hp1[(6+ch)*32];
      short8 bv = *(const short8*)&wp[320 + ch*32];
      acc0 = __builtin_amdgcn_mfma_f32_16x16x32_bf16(a0, bv, acc0, 0,0,0);
      acc1 = __builtin_amdgcn_mfma_f32_16x16x32_bf16(a1, bv, acc1, 0,0,0);
    }
  }
  {
    const int jj = l & 7;
    const int g  = wn*2 + ((l>>3)&1);
    #pragma unroll
    for (int r = 0; r < 4; ++r){
      gsc[kh][g][jj][wm*32 +      (l>>4)*4 + r] = acc0[r];
      gsc[kh][g][jj][wm*32 + 16 + (l>>4)*4 + r] = acc1[r];
    }
  }
  __syncthreads();
  {
    float gi = gsc[0][0][jj_e][bl_e] + gsc[1][0][jj_e][bl_e] + gdv[0] + hv_e*wrv[0];
    float gf = gsc[0][1][jj_e][bl_e] + gsc[1][1][jj_e][bl_e] + gdv[1] + hv_e*wrv[1];
    float gg = gsc[0][2][jj_e][bl_e] + gsc[1][2][jj_e][bl_e] + gdv[2] + hv_e*wrv[2];
    float go = gsc[0][3][jj_e][bl_e] + gsc[1][3][jj_e][bl_e] + gdv[3] + hv_e*wrv[3];
    const size_t ci = (size_t)b_e*H + j_e;
    float cn = sigmoidf_(gf)*c_e + sigmoidf_(gi)*tanhf(gg);
    float hn = sigmoidf_(go)*tanhf(cn);
    c[ci] = cn;
    eo16[((size_t)b_e*S + t)*H + j_e] = __float2bfloat16(hn);
  }
}

// ======== decoder step v5 (r13 verbatim) ========
__global__ __launch_bounds__(256) void dec_step5(
    const __hip_bfloat16* __restrict__ hin, int hs,
    const __hip_bfloat16* __restrict__ W16,
    const float* __restrict__ gdd,
    const float* __restrict__ Wy, const float* __restrict__ Wa,
    const float* __restrict__ y, const float* __restrict__ fut,
    float* __restrict__ c,
    float* __restrict__ hout32, __hip_bfloat16* __restrict__ hout16, int t)
{
  __shared__ float gsc[4][8][66];
  const int tid = threadIdx.x;
  const int id  = blockIdx.x;
  const int xcd = id & 7, sub = id >> 3;
  const int jgrp = xcd*8 + (sub & 7);
  const int bgrp = sub >> 3;
  const int b0 = bgrp*64, j0 = jgrp*8;
  const int l  = tid & 63;
  const int wid = tid >> 6, wm = wid & 1, wn = wid >> 1;
  const int lr = l & 15, lkp = (l >> 4)*8;

  float yv_[2], av_[2], c_[2], gdv[2][4], wyv[2][4], wav[2][4];
  #pragma unroll
  for (int p = 0; p < 2; ++p){
    const int pp = tid + p*256;
    const int jj = pp & 7, bl = pp >> 3;
    const int b_ = b0 + bl, j_ = j0 + jj;
    yv_[p] = y[b_];
    av_[p] = fut[(size_t)b_*16 + t];
    c_[p]  = c[(size_t)b_*H + j_];
    #pragma unroll
    for (int g = 0; g < 4; ++g){
      gdv[p][g] = gdd[(size_t)b_*G + g*512 + j_];
      wyv[p][g] = Wy[g*512 + j_];
      wav[p][g] = Wa[g*512 + j_];
    }
  }

  const int rowA0 = b0 + wm*32 + lr;
  const int rowA1 = rowA0 + 16;
  const int cc = wn*16 + lr;
  const int bn = (cc >> 3)*512 + j0 + (cc & 7);

  const __hip_bfloat16* hp0 = &hin[(size_t)rowA0*hs + lkp];
  const __hip_bfloat16* hp1 = &hin[(size_t)rowA1*hs + lkp];
  const __hip_bfloat16* wp  = &W16[(size_t)bn*512 + lkp];

  f32x4 acc0 = {0.f,0.f,0.f,0.f}, acc1 = {0.f,0.f,0.f,0.f};
  #pragma unroll
  for (int ch = 0; ch < 16; ++ch){
    short8 a0 = *(const short8*)&hp0[ch*32];
    short8 a1 = *(const short8*)&hp1[ch*32];
    short8 bv = *(const short8*)&wp[ch*32];
    acc0 = __builtin_amdgcn_mfma_f32_16x16x32_bf16(a0, bv, acc0, 0,0,0);
    acc1 = __builtin_amdgcn_mfma_f32_16x16x32_bf16(a1, bv, acc1, 0,0,0);
  }
  {
    const int jj = l & 7;
    const int g  = wn*2 + ((l>>3)&1);
    #pragma unroll
    for (int r = 0; r < 4; ++r){
      gsc[g][jj][wm*32 +      (l>>4)*4 + r] = acc0[r];
      gsc[g][jj][wm*32 + 16 + (l>>4)*4 + r] = acc1[r];
    }
  }
  __syncthreads();
  #pragma unroll
  for (int p = 0; p < 2; ++p){
    const int pp = tid + p*256;
    const int jj = pp & 7, bl = pp >> 3;
    const int b_ = b0 + bl, j_ = j0 + jj;
    float gi = gsc[0][jj][bl] + gdv[p][0] + yv_[p]*wyv[p][0] + av_[p]*wav[p][0];
    float gf = gsc[1][jj][bl] + gdv[p][1] + yv_[p]*wyv[p][1] + av_[p]*wav[p][1];
    float gg = gsc[2][jj][bl] + gdv[p][2] + yv_[p]*wyv[p][2] + av_[p]*wav[p][2];
    float go = gsc[3][jj][bl] + gdv[p][3] + yv_[p]*wyv[p][3] + av_[p]*wav[p][3];
    const size_t ci = (size_t)b_*H + j_;
    float cn = sigmoidf_(gf)*c_[p] + sigmoidf_(gi)*tanhf(gg);
    float hn = sigmoidf_(go)*tanhf(cn);
    c[ci] = cn;
    hout32[ci] = hn;
    hout16[ci] = __float2bfloat16(hn);
  }
}

// ------- propensity + enc_We + nu (r13 verbatim) -------
__global__ __launch_bounds__(256) void prop_we_kernel(
    const __hip_bfloat16* __restrict__ eo, const float* __restrict__ propW,
    const float* __restrict__ propb, const float* __restrict__ attnW,
    const float* __restrict__ owc,
    float* __restrict__ prop_out, float* __restrict__ encWe,
    float* __restrict__ nu)
{
  int row = blockIdx.x*4 + (threadIdx.x >> 6);
  int lane = threadIdx.x & 63;
  const __hip_bfloat16* e = &eo[(size_t)row*H];
  float ap = 0.f, aw = 0.f, an = 0.f;
  #pragma unroll
  for (int i = 0; i < 8; ++i){
    float v = __bfloat162float(e[lane + i*64]);
    ap += v*propW[lane + i*64];
    aw += v*attnW[512 + lane + i*64];
    an += v*owc[lane + i*64];
  }
  #pragma unroll
  for (int off = 32; off; off >>= 1){
    ap += __shfl_down(ap, off); aw += __shfl_down(aw, off); an += __shfl_down(an, off);
  }
  if (lane == 0){
    prop_out[row] = ap + propb[0];
    encWe[row] = aw;
    nu[row] = an;
  }
}

// ---------------- attention v3 (r13 verbatim) ----------------
__global__ __launch_bounds__(512) void attn_pred3(
    const __hip_bfloat16* __restrict__ eo, const float* __restrict__ encWe,
    const float* __restrict__ nu, const float* __restrict__ h,
    const float* __restrict__ attnW, const float* __restrict__ attnb,
    const float* __restrict__ outW, const float* __restrict__ outb,
    const float* __restrict__ fut,
    float* __restrict__ y, float* __restrict__ out, int t)
{
  __shared__ float hWi[512];
  __shared__ float sc[128];
  __shared__ float enl[128], nul[128];
  __shared__ float wpart[8];
  __shared__ float smax_s, ssum_s, sdot_s;
  const int b = blockIdx.x, tid = threadIdx.x;
  const int l = tid & 63, wid = tid >> 6;

  const float hv = h[(size_t)b*H + tid];
  hWi[tid] = hv * attnW[1024 + tid];
  if (tid < 128) enl[tid] = encWe[(size_t)b*S + tid];
  else if (tid < 256) nul[tid - 128] = nu[(size_t)b*S + tid - 128];

  float r = hv * attnW[tid];
  #pragma unroll
  for (int off = 32; off; off >>= 1) r += __shfl_down(r, off);
  if (l == 0) wpart[wid] = r;
  __syncthreads();
  float sWh = attnb[0];
  #pragma unroll
  for (int w = 0; w < 8; ++w) sWh += wpart[w];

  const int sg  = l >> 3;
  const int dlo = (l & 7) * 8;
  #pragma unroll
  for (int p = 0; p < 2; ++p){
    const int s = p*64 + wid*8 + sg;
    const __hip_bfloat16* erow = &eo[((size_t)b*S + s)*H];
    short8 ev[8];
    #pragma unroll
    for (int i = 0; i < 8; ++i) ev[i] = *(const short8*)&erow[dlo + i*64];
    float a = 0.f;
    #pragma unroll
    for (int i = 0; i < 8; ++i){
      #pragma unroll
      for (int k = 0; k < 8; ++k)
        a += bf2f_((unsigned short)ev[i][k]) * hWi[dlo + i*64 + k];
    }
    a += __shfl_xor(a, 4);
    a += __shfl_xor(a, 2);
    a += __shfl_xor(a, 1);
    if ((l & 7) == 0) sc[s] = tanhf(sWh + enl[s] + a);
  }
  __syncthreads();

  if (tid < 64){
    float m = fmaxf(sc[tid], sc[tid + 64]);
    #pragma unroll
    for (int off = 32; off; off >>= 1) m = fmaxf(m, __shfl_down(m, off));
    if (tid == 0) smax_s = m;
  }
  __syncthreads();
  if (tid < 64){
    float e0 = expf(sc[tid] - smax_s), e1 = expf(sc[tid + 64] - smax_s);
    float ss = e0 + e1;
    float sd = e0*nul[tid] + e1*nul[tid + 64];
    #pragma unroll
    for (int off = 32; off; off >>= 1){ ss += __shfl_down(ss, off); sd += __shfl_down(sd, off); }
    if (tid == 0){ ssum_s = ss; sdot_s = sd; }
  }

  float r2 = hv * outW[tid];
  #pragma unroll
  for (int off = 32; off; off >>= 1) r2 += __shfl_down(r2, off);
  __syncthreads();
  if (l == 0) wpart[wid] = r2;
  __syncthreads();
  if (tid == 0){
    float at = fut[(size_t)b*16 + t];
    float p = wpart[0]+wpart[1]+wpart[2]+wpart[3]+wpart[4]+wpart[5]+wpart[6]+wpart[7]
            + sdot_s / ssum_s + at*outW[1024] + outb[0];
    y[b] = p;
    out[(size_t)b*16 + t] = p;
  }
}

extern "C" void kernel_launch(void* const* d_in, const int* in_sizes, int n_in,
                              void* d_out, int out_size, void* d_ws, size_t ws_size,
                              hipStream_t stream)
{
  const float* temporal_x = (const float*)d_in[0];
  const float* static_x   = (const float*)d_in[1];
  const float* hist       = (const float*)d_in[2];
  const float* fut        = (const float*)d_in[3];
  const float* fio        = (const float*)d_in[4];
  const float* temp_W = (const float*)d_in[5];
  const float* temp_b = (const float*)d_in[6];
  const float* stat_W = (const float*)d_in[7];
  const float* stat_b = (const float*)d_in[8];
  const float* eWih = (const float*)d_in[9];
  const float* eWhh = (const float*)d_in[10];
  const float* eb   = (const float*)d_in[11];
  const float* attnW = (const float*)d_in[12];
  const float* attnb = (const float*)d_in[13];
  const float* dWih = (const float*)d_in[14];
  const float* dWhh = (const float*)d_in[15];
  const float* dbias = (const float*)d_in[16];
  const float* outW = (const float*)d_in[17];
  const float* outb = (const float*)d_in[18];
  const float* propW = (const float*)d_in[19];
  const float* propb = (const float*)d_in[20];
  float* out = (float*)d_out;   // fp32: [B*16 preds][B*S propensity]

  // ---- workspace layout ----
  float* ws = (float*)d_ws;
  float* ed    = ws;                           // B*128
  float* gd_e  = ed    + (size_t)B*128;        // B*G
  float* gd_d  = gd_e  + (size_t)B*G;          // B*G
  float* cb    = gd_d  + (size_t)B*G;          // B*H
  float* encWe = cb    + (size_t)B*H;          // B*S
  float* nub   = encWe + (size_t)B*S;          // B*S
  float* yb    = nub   + (size_t)B*S;          // B
  float* dh32  = yb    + B;                    // B*H
  int*   flg   = (int*)(dh32 + (size_t)B*H);   // 512 ints
  __hip_bfloat16* bf = (__hip_bfloat16*)(flg + 512);
  __hip_bfloat16* ex16 = bf;                              // B*S*128
  __hip_bfloat16* eo16 = ex16 + (size_t)B*S*128;          // B*S*H
  __hip_bfloat16* h16A = eo16 + (size_t)B*S*H;            // B*H
  __hip_bfloat16* h16B = h16A + (size_t)B*H;              // B*H
  __hip_bfloat16* W16E = h16B + (size_t)B*H;              // 2048*640
  __hip_bfloat16* W16D = W16E + (size_t)G*640;            // 2048*512

  init_kernel<<<(B*H + 255)/256, 256, 0, stream>>>(cb, (unsigned*)h16A, (unsigned*)h16B,
                                                   flg, yb, fio);
  embed_x4<<<2048, 128, 0, stream>>>(temporal_x, temp_W, temp_b, ex16);
  embed_d_kernel<<<B, 128, 0, stream>>>(static_x, stat_W, stat_b, ed);
  gd2_kernel<<<dim3(B,8), 256, 0, stream>>>(ed, eWih, eb, dWih, dbias, gd_e, gd_d);
  wtrans_kernel<<<dim3(10,32), 256, 0, stream>>>(eWih, 128, eWhh, W16E, 640);
  wtrans_kernel<<<dim3(8,32),  256, 0, stream>>>(dWhh, 0,   dWhh, W16D, 512);

  const float* wr256p = eWih + (size_t)256*G;

  // ---- persistent flag-synced encoder; fallback to per-step loop on error ----
  {
    const __hip_bfloat16* ex16c = ex16;
    const __hip_bfloat16* W16Ec = W16E;
    const float* gd_ec = gd_e;
    const float* histc = hist;
    float* cbp = cb;
    __hip_bfloat16* hAp = h16A;
    __hip_bfloat16* hBp = h16B;
    __hip_bfloat16* eo16p = eo16;
    int* flgp = flg;
    void* args[] = {(void*)&ex16c, (void*)&W16Ec, (void*)&gd_ec, (void*)&wr256p,
                    (void*)&histc, (void*)&cbp, (void*)&hAp, (void*)&hBp,
                    (void*)&eo16p, (void*)&flgp};
    hipError_t cerr = hipLaunchCooperativeKernel((const void*)enc_persist2,
                                                 dim3(256), dim3(512), args, 0, stream);
    if (cerr != hipSuccess){
      for (int t = 0; t < S; ++t){
        const __hip_bfloat16* hin = (t == 0) ? h16A : (eo16 + (size_t)(t-1)*H);
        const int hs = (t == 0) ? H : S*H;
        enc_step7<<<256, 512, 0, stream>>>(ex16, hin, hs, W16E, gd_e, wr256p,
                                           hist, cb, eo16, t);
      }
    }
  }

  prop_we_kernel<<<(B*S)/4, 256, 0, stream>>>(eo16, propW, propb, attnW, outW + 512,
                                              out + B*16, encWe, nub);

  // decoder: t=0 reads h_n = eo16[:,S-1,:]; then ping-pong h16B/h16A.
  for (int t = 0; t < 16; ++t){
    const __hip_bfloat16* hin; int hs;
    if (t == 0){ hin = eo16 + (size_t)(S-1)*H; hs = S*H; }
    else { hin = (t & 1) ? h16B : h16A; hs = H; }
    __hip_bfloat16* hout16 = (t & 1) ? h16A : h16B;
    dec_step5<<<256, 256, 0, stream>>>(hin, hs, W16D, gd_d,
                                       dWih + (size_t)128*G, dWih + (size_t)129*G,
                                       yb, fut, cb, dh32, hout16, t);
    attn_pred3<<<B, 512, 0, stream>>>(eo16, encWe, nub, dh32, attnW, attnb, outW, outb,
                                      fut, yb, out, t);
  }
}

// Round 15
// 1502.943 us; speedup vs baseline: 1.4534x; 1.4534x over previous
//
#include <hip/hip_runtime.h>
#include <hip/hip_bf16.h>
#include <cstddef>

#define B 256
#define S 128
#define H 512
#define G 2048

typedef __attribute__((ext_vector_type(8))) short short8;
typedef __attribute__((ext_vector_type(4))) float f32x4;

__device__ __forceinline__ float sigmoidf_(float x){ return 1.f/(1.f+expf(-x)); }
__device__ __forceinline__ float bf2f_(unsigned short u){ return __uint_as_float(((unsigned)u) << 16); }

// ---------------- init: zero c and h16A, y = future_init_outcome ----------------
__global__ void init_kernel(float* __restrict__ c, unsigned* __restrict__ h16A_u,
                            float* __restrict__ y, const float* __restrict__ fio){
  int i = blockIdx.x*blockDim.x + threadIdx.x;
  if (i < B*H) c[i] = 0.f;
  if (i < B*H/2) h16A_u[i] = 0u;      // two bf16 zeros (enc t=0 reads h=0)
  if (i < B) y[i] = fio[i];
}

// ------- e_x v4 (r13 verbatim) -------
__global__ __launch_bounds__(128) void embed_x4(const float* __restrict__ tx,
    const float* __restrict__ W, const float* __restrict__ bvec,
    __hip_bfloat16* __restrict__ ex16){
  __shared__ float xs[16][64];
  const int tid = threadIdx.x;
  float w[64];
  #pragma unroll
  for (int k = 0; k < 64; ++k) w[k] = W[k*128 + tid];
  const float bj = bvec[tid];
  const int r0 = blockIdx.x * 16;
  {
    const float4* src = (const float4*)&tx[(size_t)r0*64];
    float4* dst = (float4*)&xs[0][0];
    dst[tid] = src[tid];
    dst[tid + 128] = src[tid + 128];
  }
  __syncthreads();
  #pragma unroll
  for (int r = 0; r < 16; ++r){
    const float4* xr = (const float4*)&xs[r][0];
    float a0 = 0.f, a1 = 0.f, a2 = 0.f, a3 = 0.f;
    #pragma unroll
    for (int q = 0; q < 16; ++q){
      float4 xv = xr[q];
      a0 += xv.x*w[q*4+0];
      a1 += xv.y*w[q*4+1];
      a2 += xv.z*w[q*4+2];
      a3 += xv.w*w[q*4+3];
    }
    float a = bj + (a0 + a1) + (a2 + a3);
    ex16[(size_t)(r0 + r)*128 + tid] = __float2bfloat16(fmaxf(a, 0.f));
  }
}

// ---- gd2e: computes e_d inline, then BOTH gd_e and gd_d, stored bf16 ----
__global__ __launch_bounds__(256) void gd2e_kernel(const float* __restrict__ sx,
    const float* __restrict__ statW, const float* __restrict__ statb,
    const float* __restrict__ We, const float* __restrict__ be,
    const float* __restrict__ Wd, const float* __restrict__ bd,
    __hip_bfloat16* __restrict__ gde, __hip_bfloat16* __restrict__ gdd){
  __shared__ float xs[32];
  __shared__ float eds[128];
  int b = blockIdx.x, tid = threadIdx.x;
  if (tid < 32) xs[tid] = sx[(size_t)b*32 + tid];
  __syncthreads();
  if (tid < 128){
    float a = statb[tid];
    #pragma unroll 8
    for (int k = 0; k < 32; ++k) a += xs[k]*statW[k*128 + tid];
    eds[tid] = fmaxf(a, 0.f);
  }
  __syncthreads();
  int n = blockIdx.y*256 + tid;
  float ae = be[n], ad = bd[n];
  #pragma unroll 4
  for (int k = 0; k < 128; ++k){
    float e = eds[k];
    ae += e*We[(size_t)(128 + k)*G + n];
    ad += e*Wd[(size_t)k*G + n];
  }
  gde[(size_t)b*G + n] = __float2bfloat16(ae);
  gdd[(size_t)b*G + n] = __float2bfloat16(ad);
}

// ---- weight transpose (r13 verbatim) ----
__global__ __launch_bounds__(256) void wtrans_kernel(
    const float* __restrict__ A, int rowsA, const float* __restrict__ Bm,
    __hip_bfloat16* __restrict__ dst, int Ktot)
{
  __shared__ float tile[64][65];
  const int k0 = blockIdx.x*64, n0 = blockIdx.y*64;
  const int tid = threadIdx.x;
  const int tn = tid & 63, tq = tid >> 6;
  #pragma unroll
  for (int i = 0; i < 16; ++i){
    int k = k0 + tq*16 + i;
    float v = (k < rowsA) ? A[(size_t)k*G + n0 + tn] : Bm[(size_t)(k-rowsA)*G + n0 + tn];
    tile[k - k0][tn] = v;
  }
  __syncthreads();
  #pragma unroll
  for (int i = 0; i < 16; ++i){
    int n = n0 + tq*16 + i;
    dst[(size_t)n*Ktot + k0 + tn] = __float2bfloat16(tile[tn][tq*16 + i]);
  }
}

// ======== encoder step v7 (r13 structure; gd now bf16) ========
__global__ __launch_bounds__(512) void enc_step7(
    const __hip_bfloat16* __restrict__ ex16,   // [B][S][128]
    const __hip_bfloat16* __restrict__ hin,    // h(t-1), row stride hs
    int hs,
    const __hip_bfloat16* __restrict__ W16,    // [2048][640] n-major
    const __hip_bfloat16* __restrict__ gd,     // [B][2048] bf16
    const float* __restrict__ Wr256,           // fp32 row Wih[256][*]
    const float* __restrict__ hist,            // [B][S]
    float* __restrict__ c,
    __hip_bfloat16* __restrict__ eo16, int t)
{
  __shared__ float gsc[2][4][8][66];           // [kh][gate][jj][row]
  const int tid = threadIdx.x;
  const int id  = blockIdx.x;
  const int xcd = id & 7, sub = id >> 3;
  const int jgrp = xcd*8 + (sub & 7);          // 0..63
  const int bgrp = sub >> 3;                   // 0..3
  const int b0 = bgrp*64, j0 = jgrp*8;
  const int l  = tid & 63;
  const int wid = tid >> 6;                    // 0..7
  const int kh = wid & 1, wm = (wid >> 1) & 1, wn = wid >> 2;
  const int lr = l & 15, lkp = (l >> 4)*8;

  const int jj_e = tid & 7, bl_e = tid >> 3;   // bl_e 0..63
  const int b_e = b0 + bl_e, j_e = j0 + jj_e;
  const float hv_e = hist[(size_t)b_e*S + t];
  const float c_e  = c[(size_t)b_e*H + j_e];
  float gdv[4], wrv[4];
  #pragma unroll
  for (int g = 0; g < 4; ++g){
    gdv[g] = __bfloat162float(gd[(size_t)b_e*G + g*512 + j_e]);
    wrv[g] = Wr256[g*512 + j_e];
  }

  const int rowA0 = b0 + wm*32 + lr;
  const int rowA1 = rowA0 + 16;
  const int cc = wn*16 + lr;                   // 0..31
  const int bn = (cc >> 3)*512 + j0 + (cc & 7);

  const __hip_bfloat16* ep0 = &ex16[((size_t)rowA0*S + t)*128 + lkp];
  const __hip_bfloat16* ep1 = &ex16[((size_t)rowA1*S + t)*128 + lkp];
  const __hip_bfloat16* hp0 = &hin[(size_t)rowA0*hs + lkp];
  const __hip_bfloat16* hp1 = &hin[(size_t)rowA1*hs + lkp];
  const __hip_bfloat16* wp  = &W16[(size_t)bn*640 + lkp];

  f32x4 acc0 = {0.f,0.f,0.f,0.f}, acc1 = {0.f,0.f,0.f,0.f};
  if (kh == 0){
    #pragma unroll
    for (int ch = 0; ch < 4; ++ch){
      short8 a0 = *(const short8*)&ep0[ch*32];
      short8 a1 = *(const short8*)&ep1[ch*32];
      short8 bv = *(const short8*)&wp[ch*32];
      acc0 = __builtin_amdgcn_mfma_f32_16x16x32_bf16(a0, bv, acc0, 0,0,0);
      acc1 = __builtin_amdgcn_mfma_f32_16x16x32_bf16(a1, bv, acc1, 0,0,0);
    }
    #pragma unroll
    for (int ch = 0; ch < 6; ++ch){
      short8 a0 = *(const short8*)&hp0[ch*32];
      short8 a1 = *(const short8*)&hp1[ch*32];
      short8 bv = *(const short8*)&wp[128 + ch*32];
      acc0 = __builtin_amdgcn_mfma_f32_16x16x32_bf16(a0, bv, acc0, 0,0,0);
      acc1 = __builtin_amdgcn_mfma_f32_16x16x32_bf16(a1, bv, acc1, 0,0,0);
    }
  } else {
    #pragma unroll
    for (int ch = 0; ch < 10; ++ch){
      short8 a0 = *(const short8*)&hp0[(6+ch)*32];
      short8 a1 = *(const short8*)&hp1[(6+ch)*32];
      short8 bv = *(const short8*)&wp[320 + ch*32];
      acc0 = __builtin_amdgcn_mfma_f32_16x16x32_bf16(a0, bv, acc0, 0,0,0);
      acc1 = __builtin_amdgcn_mfma_f32_16x16x32_bf16(a1, bv, acc1, 0,0,0);
    }
  }

  {
    const int jj = l & 7;
    const int g  = wn*2 + ((l>>3)&1);
    #pragma unroll
    for (int r = 0; r < 4; ++r){
      gsc[kh][g][jj][wm*32 +      (l>>4)*4 + r] = acc0[r];
      gsc[kh][g][jj][wm*32 + 16 + (l>>4)*4 + r] = acc1[r];
    }
  }
  __syncthreads();

  {
    float gi = gsc[0][0][jj_e][bl_e] + gsc[1][0][jj_e][bl_e] + gdv[0] + hv_e*wrv[0];
    float gf = gsc[0][1][jj_e][bl_e] + gsc[1][1][jj_e][bl_e] + gdv[1] + hv_e*wrv[1];
    float gg = gsc[0][2][jj_e][bl_e] + gsc[1][2][jj_e][bl_e] + gdv[2] + hv_e*wrv[2];
    float go = gsc[0][3][jj_e][bl_e] + gsc[1][3][jj_e][bl_e] + gdv[3] + hv_e*wrv[3];
    const size_t ci = (size_t)b_e*H + j_e;
    float cn = sigmoidf_(gf)*c_e + sigmoidf_(gi)*tanhf(gg);
    float hn = sigmoidf_(go)*tanhf(cn);
    c[ci] = cn;
    eo16[((size_t)b_e*S + t)*H + j_e] = __float2bfloat16(hn);
  }
}

// ======== decoder step v5 (r13 structure; gdd now bf16) ========
__global__ __launch_bounds__(256) void dec_step5(
    const __hip_bfloat16* __restrict__ hin, int hs,
    const __hip_bfloat16* __restrict__ W16,    // [2048][512] n-major
    const __hip_bfloat16* __restrict__ gdd,    // [B][2048] bf16
    const float* __restrict__ Wy, const float* __restrict__ Wa,
    const float* __restrict__ y, const float* __restrict__ fut,
    float* __restrict__ c,
    float* __restrict__ hout32, __hip_bfloat16* __restrict__ hout16, int t)
{
  __shared__ float gsc[4][8][66];
  const int tid = threadIdx.x;
  const int id  = blockIdx.x;
  const int xcd = id & 7, sub = id >> 3;
  const int jgrp = xcd*8 + (sub & 7);
  const int bgrp = sub >> 3;
  const int b0 = bgrp*64, j0 = jgrp*8;
  const int l  = tid & 63;
  const int wid = tid >> 6, wm = wid & 1, wn = wid >> 1;
  const int lr = l & 15, lkp = (l >> 4)*8;

  float yv_[2], av_[2], c_[2], gdv[2][4], wyv[2][4], wav[2][4];
  #pragma unroll
  for (int p = 0; p < 2; ++p){
    const int pp = tid + p*256;
    const int jj = pp & 7, bl = pp >> 3;
    const int b_ = b0 + bl, j_ = j0 + jj;
    yv_[p] = y[b_];
    av_[p] = fut[(size_t)b_*16 + t];
    c_[p]  = c[(size_t)b_*H + j_];
    #pragma unroll
    for (int g = 0; g < 4; ++g){
      gdv[p][g] = __bfloat162float(gdd[(size_t)b_*G + g*512 + j_]);
      wyv[p][g] = Wy[g*512 + j_];
      wav[p][g] = Wa[g*512 + j_];
    }
  }

  const int rowA0 = b0 + wm*32 + lr;
  const int rowA1 = rowA0 + 16;
  const int cc = wn*16 + lr;
  const int bn = (cc >> 3)*512 + j0 + (cc & 7);

  const __hip_bfloat16* hp0 = &hin[(size_t)rowA0*hs + lkp];
  const __hip_bfloat16* hp1 = &hin[(size_t)rowA1*hs + lkp];
  const __hip_bfloat16* wp  = &W16[(size_t)bn*512 + lkp];

  f32x4 acc0 = {0.f,0.f,0.f,0.f}, acc1 = {0.f,0.f,0.f,0.f};
  #pragma unroll
  for (int ch = 0; ch < 16; ++ch){
    short8 a0 = *(const short8*)&hp0[ch*32];
    short8 a1 = *(const short8*)&hp1[ch*32];
    short8 bv = *(const short8*)&wp[ch*32];
    acc0 = __builtin_amdgcn_mfma_f32_16x16x32_bf16(a0, bv, acc0, 0,0,0);
    acc1 = __builtin_amdgcn_mfma_f32_16x16x32_bf16(a1, bv, acc1, 0,0,0);
  }
  {
    const int jj = l & 7;
    const int g  = wn*2 + ((l>>3)&1);
    #pragma unroll
    for (int r = 0; r < 4; ++r){
      gsc[g][jj][wm*32 +      (l>>4)*4 + r] = acc0[r];
      gsc[g][jj][wm*32 + 16 + (l>>4)*4 + r] = acc1[r];
    }
  }
  __syncthreads();
  #pragma unroll
  for (int p = 0; p < 2; ++p){
    const int pp = tid + p*256;
    const int jj = pp & 7, bl = pp >> 3;
    const int b_ = b0 + bl, j_ = j0 + jj;
    float gi = gsc[0][jj][bl] + gdv[p][0] + yv_[p]*wyv[p][0] + av_[p]*wav[p][0];
    float gf = gsc[1][jj][bl] + gdv[p][1] + yv_[p]*wyv[p][1] + av_[p]*wav[p][1];
    float gg = gsc[2][jj][bl] + gdv[p][2] + yv_[p]*wyv[p][2] + av_[p]*wav[p][2];
    float go = gsc[3][jj][bl] + gdv[p][3] + yv_[p]*wyv[p][3] + av_[p]*wav[p][3];
    const size_t ci = (size_t)b_*H + j_;
    float cn = sigmoidf_(gf)*c_[p] + sigmoidf_(gi)*tanhf(gg);
    float hn = sigmoidf_(go)*tanhf(cn);
    c[ci] = cn;
    hout32[ci] = hn;
    hout16[ci] = __float2bfloat16(hn);
  }
}

// ------- propensity + enc_We + nu (r13 verbatim) -------
__global__ __launch_bounds__(256) void prop_we_kernel(
    const __hip_bfloat16* __restrict__ eo, const float* __restrict__ propW,
    const float* __restrict__ propb, const float* __restrict__ attnW,
    const float* __restrict__ owc,
    float* __restrict__ prop_out, float* __restrict__ encWe,
    float* __restrict__ nu)
{
  int row = blockIdx.x*4 + (threadIdx.x >> 6);
  int lane = threadIdx.x & 63;
  const __hip_bfloat16* e = &eo[(size_t)row*H];
  float ap = 0.f, aw = 0.f, an = 0.f;
  #pragma unroll
  for (int i = 0; i < 8; ++i){
    float v = __bfloat162float(e[lane + i*64]);
    ap += v*propW[lane + i*64];
    aw += v*attnW[512 + lane + i*64];
    an += v*owc[lane + i*64];
  }
  #pragma unroll
  for (int off = 32; off; off >>= 1){
    ap += __shfl_down(ap, off); aw += __shfl_down(aw, off); an += __shfl_down(an, off);
  }
  if (lane == 0){
    prop_out[row] = ap + propb[0];
    encWe[row] = aw;
    nu[row] = an;
  }
}

// ---------------- attention v3 (r13 verbatim) ----------------
__global__ __launch_bounds__(512) void attn_pred3(
    const __hip_bfloat16* __restrict__ eo, const float* __restrict__ encWe,
    const float* __restrict__ nu, const float* __restrict__ h,
    const float* __restrict__ attnW, const float* __restrict__ attnb,
    const float* __restrict__ outW, const float* __restrict__ outb,
    const float* __restrict__ fut,
    float* __restrict__ y, float* __restrict__ out, int t)
{
  __shared__ float hWi[512];
  __shared__ float sc[128];
  __shared__ float enl[128], nul[128];
  __shared__ float wpart[8];
  __shared__ float smax_s, ssum_s, sdot_s;
  const int b = blockIdx.x, tid = threadIdx.x;
  const int l = tid & 63, wid = tid >> 6;

  const float hv = h[(size_t)b*H + tid];
  hWi[tid] = hv * attnW[1024 + tid];
  if (tid < 128) enl[tid] = encWe[(size_t)b*S + tid];
  else if (tid < 256) nul[tid - 128] = nu[(size_t)b*S + tid - 128];

  float r = hv * attnW[tid];
  #pragma unroll
  for (int off = 32; off; off >>= 1) r += __shfl_down(r, off);
  if (l == 0) wpart[wid] = r;
  __syncthreads();
  float sWh = attnb[0];
  #pragma unroll
  for (int w = 0; w < 8; ++w) sWh += wpart[w];

  const int sg  = l >> 3;
  const int dlo = (l & 7) * 8;
  #pragma unroll
  for (int p = 0; p < 2; ++p){
    const int s = p*64 + wid*8 + sg;
    const __hip_bfloat16* erow = &eo[((size_t)b*S + s)*H];
    short8 ev[8];
    #pragma unroll
    for (int i = 0; i < 8; ++i) ev[i] = *(const short8*)&erow[dlo + i*64];
    float a = 0.f;
    #pragma unroll
    for (int i = 0; i < 8; ++i){
      #pragma unroll
      for (int k = 0; k < 8; ++k)
        a += bf2f_((unsigned short)ev[i][k]) * hWi[dlo + i*64 + k];
    }
    a += __shfl_xor(a, 4);
    a += __shfl_xor(a, 2);
    a += __shfl_xor(a, 1);
    if ((l & 7) == 0) sc[s] = tanhf(sWh + enl[s] + a);
  }
  __syncthreads();

  if (tid < 64){
    float m = fmaxf(sc[tid], sc[tid + 64]);
    #pragma unroll
    for (int off = 32; off; off >>= 1) m = fmaxf(m, __shfl_down(m, off));
    if (tid == 0) smax_s = m;
  }
  __syncthreads();
  if (tid < 64){
    float e0 = expf(sc[tid] - smax_s), e1 = expf(sc[tid + 64] - smax_s);
    float ss = e0 + e1;
    float sd = e0*nul[tid] + e1*nul[tid + 64];
    #pragma unroll
    for (int off = 32; off; off >>= 1){ ss += __shfl_down(ss, off); sd += __shfl_down(sd, off); }
    if (tid == 0){ ssum_s = ss; sdot_s = sd; }
  }

  float r2 = hv * outW[tid];
  #pragma unroll
  for (int off = 32; off; off >>= 1) r2 += __shfl_down(r2, off);
  __syncthreads();
  if (l == 0) wpart[wid] = r2;
  __syncthreads();
  if (tid == 0){
    float at = fut[(size_t)b*16 + t];
    float p = wpart[0]+wpart[1]+wpart[2]+wpart[3]+wpart[4]+wpart[5]+wpart[6]+wpart[7]
            + sdot_s / ssum_s + at*outW[1024] + outb[0];
    y[b] = p;
    out[(size_t)b*16 + t] = p;
  }
}

extern "C" void kernel_launch(void* const* d_in, const int* in_sizes, int n_in,
                              void* d_out, int out_size, void* d_ws, size_t ws_size,
                              hipStream_t stream)
{
  const float* temporal_x = (const float*)d_in[0];
  const float* static_x   = (const float*)d_in[1];
  const float* hist       = (const float*)d_in[2];
  const float* fut        = (const float*)d_in[3];
  const float* fio        = (const float*)d_in[4];
  const float* temp_W = (const float*)d_in[5];
  const float* temp_b = (const float*)d_in[6];
  const float* stat_W = (const float*)d_in[7];
  const float* stat_b = (const float*)d_in[8];
  const float* eWih = (const float*)d_in[9];
  const float* eWhh = (const float*)d_in[10];
  const float* eb   = (const float*)d_in[11];
  const float* attnW = (const float*)d_in[12];
  const float* attnb = (const float*)d_in[13];
  const float* dWih = (const float*)d_in[14];
  const float* dWhh = (const float*)d_in[15];
  const float* dbias = (const float*)d_in[16];
  const float* outW = (const float*)d_in[17];
  const float* outb = (const float*)d_in[18];
  const float* propW = (const float*)d_in[19];
  const float* propb = (const float*)d_in[20];
  float* out = (float*)d_out;   // fp32: [B*16 preds][B*S propensity]

  // ---- workspace layout: fp32 section then bf16 section (~50.6 MB) ----
  float* ws = (float*)d_ws;
  float* cb    = ws;                           // B*H
  float* encWe = cb    + (size_t)B*H;          // B*S
  float* nub   = encWe + (size_t)B*S;          // B*S
  float* yb    = nub   + (size_t)B*S;          // B
  float* dh32  = yb    + B;                    // B*H
  __hip_bfloat16* bf = (__hip_bfloat16*)(dh32 + (size_t)B*H);
  __hip_bfloat16* ex16 = bf;                              // B*S*128
  __hip_bfloat16* eo16 = ex16 + (size_t)B*S*128;          // B*S*H
  __hip_bfloat16* h16A = eo16 + (size_t)B*S*H;            // B*H (enc t=0 zeros; dec ping)
  __hip_bfloat16* h16B = h16A + (size_t)B*H;              // B*H (dec pong)
  __hip_bfloat16* W16E = h16B + (size_t)B*H;              // 2048*640
  __hip_bfloat16* W16D = W16E + (size_t)G*640;            // 2048*512
  __hip_bfloat16* gdE  = W16D + (size_t)G*512;            // B*G bf16
  __hip_bfloat16* gdD  = gdE  + (size_t)B*G;              // B*G bf16

  init_kernel<<<(B*H + 255)/256, 256, 0, stream>>>(cb, (unsigned*)h16A, yb, fio);
  embed_x4<<<2048, 128, 0, stream>>>(temporal_x, temp_W, temp_b, ex16);
  gd2e_kernel<<<dim3(B,8), 256, 0, stream>>>(static_x, stat_W, stat_b,
                                             eWih, eb, dWih, dbias, gdE, gdD);
  wtrans_kernel<<<dim3(10,32), 256, 0, stream>>>(eWih, 128, eWhh, W16E, 640);
  wtrans_kernel<<<dim3(8,32),  256, 0, stream>>>(dWhh, 0,   dWhh, W16D, 512);

  const float* wr256p = eWih + (size_t)256*G;

  // encoder: h(t) lives in eo16[:,t,:]; t=0 reads zeroed h16A.
  for (int t = 0; t < S; ++t){
    const __hip_bfloat16* hin = (t == 0) ? h16A : (eo16 + (size_t)(t-1)*H);
    const int hs = (t == 0) ? H : S*H;
    enc_step7<<<256, 512, 0, stream>>>(ex16, hin, hs, W16E, gdE, wr256p,
                                       hist, cb, eo16, t);
  }

  prop_we_kernel<<<(B*S)/4, 256, 0, stream>>>(eo16, propW, propb, attnW, outW + 512,
                                              out + B*16, encWe, nub);

  // decoder: t=0 reads h_n = eo16[:,S-1,:]; then ping-pong h16B/h16A.
  for (int t = 0; t < 16; ++t){
    const __hip_bfloat16* hin; int hs;
    if (t == 0){ hin = eo16 + (size_t)(S-1)*H; hs = S*H; }
    else { hin = (t & 1) ? h16B : h16A; hs = H; }
    __hip_bfloat16* hout16 = (t & 1) ? h16A : h16B;
    dec_step5<<<256, 256, 0, stream>>>(hin, hs, W16D, gdD,
                                       dWih + (size_t)128*G, dWih + (size_t)129*G,
                                       yb, fut, cb, dh32, hout16, t);
    attn_pred3<<<B, 512, 0, stream>>>(eo16, encWe, nub, dh32, attnW, attnb, outW, outb,
                                      fut, yb, out, t);
  }
}